// Round 7
// baseline (370.920 us; speedup 1.0000x reference)
//
#include <hip/hip_runtime.h>

#define RR 12
#define LL 1728
#define CC 768
#define HEADS 12
#define HD 64
#define BATCH 4

typedef __attribute__((ext_vector_type(8))) short bf8;   // 8 x bf16
typedef __attribute__((ext_vector_type(4))) float f4;    // 4 x fp32

__device__ inline unsigned short f2bf(float x) {         // RNE-ish
  unsigned int u = __float_as_uint(x);
  return (unsigned short)((u + 0x7FFFu + ((u >> 16) & 1u)) >> 16);
}
__device__ inline unsigned short f2bfr(float x) {        // round-half-up (cheap)
  return (unsigned short)((__float_as_uint(x) + 0x8000u) >> 16);
}

__device__ inline float fast_exp2(float x) {
#if __has_builtin(__builtin_amdgcn_exp2f)
  return __builtin_amdgcn_exp2f(x);
#else
  return exp2f(x);
#endif
}

// async 16B global->LDS (wave-uniform LDS base + lane*16)
__device__ inline void gld16(const unsigned short* g, unsigned short* l) {
  __builtin_amdgcn_global_load_lds((const __attribute__((address_space(1))) unsigned int*)g,
                                   (__attribute__((address_space(3))) unsigned int*)l, 16, 0, 0);
}

#define QSCALE 0.1803368801111244f  /* 0.125 * log2(e): folds softmax base-2 conversion in */

#define NLEPE 5184  /* 432 lines*xgroups x 3 ctiles x 4 batch */
#define NPREP 1296  /* 27 ltiles x 12 heads x 4 batch */

// ---------------- combined prep + lepe (block-uniform partition; 1 launch instead of 3) ------------
// blocks [0, NLEPE): LePE depthwise conv (4 x-positions per block — R0-proven lean shape).
// blocks [NLEPE, NLEPE+NPREP): q,k -> bf16 (q pre-scaled by QSCALE); v -> vT[b][h][d][sigma(k)].
// Slot permutation (for swapped-QK in-register P):
//   sigma(k) with k = nt*16 + quad*4 + r  ->  slot = (nt>>1)*32 + quad*8 + (nt&1)*4 + r
// Note sigma maps kv rows 0..31 -> slots 0..31 and rows 32..63 -> slots 32..63: a kv-HALF of the
// tile is exactly one K=32 PV fragment — this is what the attn kernel's wave-pair kv-split uses.
__global__ __launch_bounds__(256) void combined_kernel(const float* __restrict__ qkv,
                                                       const float* __restrict__ w,
                                                       const float* __restrict__ bias,
                                                       unsigned short* __restrict__ qb,
                                                       unsigned short* __restrict__ kb,
                                                       unsigned short* __restrict__ vT,
                                                       float* __restrict__ out) {
  __shared__ __align__(16) unsigned char smem[27648];  // union: lepe w-stage 27 KB / prep tl 8.3 KB
  const int bid = blockIdx.x;
  const int t = threadIdx.x;

  if (bid < NLEPE) {
    // ================= LePE =================
    const int xg = (bid % 3) * 4;            // x0 in {0,4,8}
    const int line = (bid / 3) % 144;        // z*12+y
    const int ct = (bid / 432) % 3;          // c-tile
    const int b = bid / 1296;
    const int z = line / RR;
    const int y = line % RR;
    const int c0 = ct * 256;
    const int c = c0 + t;
    float* w_lds = (float*)smem;

    // coalesced stage of w[c0*27 .. (c0+256)*27) as float4 (6912 floats)
    {
      const float* wsrc = w + (size_t)c0 * 27;
#pragma unroll
      for (int i = 0; i < 7; ++i) {
        const int idx = i * 256 + t;         // float4 index, 0..1727
        if (idx < 1728) *(float4*)&w_lds[idx * 4] = *(const float4*)&wsrc[idx * 4];
      }
    }
    __syncthreads();
    float wreg[27];
#pragma unroll
    for (int j = 0; j < 27; ++j) wreg[j] = w_lds[t * 27 + j];  // stride 27 ⊥ 32: 2-way, free

    const float* vb = qkv + ((size_t)(2 * BATCH + b)) * LL * CC + c;
    const float bv = bias[c];
    float acc[4] = {bv, bv, bv, bv};

#pragma unroll
    for (int dz = -1; dz <= 1; ++dz) {
#pragma unroll
      for (int dy = -1; dy <= 1; ++dy) {
        const int zz = z + dz, yy = y + dy;
        const bool lineok = ((unsigned)zz < RR) & ((unsigned)yy < RR);  // block-uniform
        const int base = (zz * RR + yy) * RR;
        float v6[6];                        // x-positions xg-1 .. xg+4, masked address-safe loads
#pragma unroll
        for (int p = 0; p < 6; ++p) {
          const int xx = xg - 1 + p;
          const bool ok = lineok & ((unsigned)xx < RR);
          const int lp = ok ? base + xx : 0;
          const float vv = vb[(size_t)lp * CC];
          v6[p] = ok ? vv : 0.f;
        }
        const int jb = ((dz + 1) * 3 + (dy + 1)) * 3;
        const float wL = wreg[jb], wC = wreg[jb + 1], wR = wreg[jb + 2];
#pragma unroll
        for (int i = 0; i < 4; ++i)
          acc[i] += wL * v6[i] + wC * v6[i + 1] + wR * v6[i + 2];
      }
    }
    const size_t obase = ((size_t)b * LL + line * RR + xg) * CC + c;
#pragma unroll
    for (int i = 0; i < 4; ++i) out[obase + (size_t)i * CC] = acc[i];

  } else {
    // ================= prep =================
    const int p = bid - NLEPE;
    const int lt = p % 27;
    const int h = (p / 27) % HEADS;
    const int b = p / (27 * HEADS);
    unsigned short* tl = (unsigned short*)smem;  // [d][l_local], stride 65

    // ---- q/k bf16 conversion for rows lt*64.., cols h*64.. ----
    {
      const int r0 = t >> 4;             // 0..15
      const int c4 = (t & 15) * 4;       // 0..60
#pragma unroll
      for (int pi = 0; pi < 4; ++pi) {
        const int row = lt * 64 + pi * 16 + r0;
        const size_t off = ((size_t)b * LL + row) * CC + h * HD + c4;
        const float4 qv = *(const float4*)(qkv + off);
        ushort4 oq;
        oq.x = f2bf(qv.x * QSCALE); oq.y = f2bf(qv.y * QSCALE);
        oq.z = f2bf(qv.z * QSCALE); oq.w = f2bf(qv.w * QSCALE);
        *(ushort4*)(qb + off) = oq;
        const float4 kv = *(const float4*)(qkv + (size_t)BATCH * LL * CC + off);
        ushort4 ok;
        ok.x = f2bf(kv.x); ok.y = f2bf(kv.y); ok.z = f2bf(kv.z); ok.w = f2bf(kv.w);
        *(ushort4*)(kb + off) = ok;
      }
    }

    // ---- vT with slot permutation ----
    const float* vsrc = qkv + ((size_t)(2 * BATCH + b)) * LL * CC;
#pragma unroll
    for (int it = 0; it < 4; ++it) {
      const int idx = it * 256 + t;
      const int lrow = idx >> 4;
      const int c4 = (idx & 15) * 4;
      const float4 vv = *(const float4*)(vsrc + (size_t)(lt * 64 + lrow) * CC + h * HD + c4);
      tl[(c4 + 0) * 65 + lrow] = f2bf(vv.x);
      tl[(c4 + 1) * 65 + lrow] = f2bf(vv.y);
      tl[(c4 + 2) * 65 + lrow] = f2bf(vv.z);
      tl[(c4 + 3) * 65 + lrow] = f2bf(vv.w);
    }
    __syncthreads();
#pragma unroll
    for (int it = 0; it < 4; ++it) {
      const int idx = it * 256 + t;
      const int drow = idx >> 4;
      const int u = idx & 15;            // slot group: s4 = u*4
      const int s4 = u * 4;
      // slots s4..s4+3 hold physical kv rows kbase..kbase+3 (consecutive):
      //   kbase = ((u>>3)*2 + (u&1))*16 + ((u>>1)&3)*4
      const int kbase = (((u >> 3) * 2 + (u & 1)) << 4) + (((u >> 1) & 3) << 2);
      ushort4 o;
      o.x = tl[drow * 65 + kbase + 0];
      o.y = tl[drow * 65 + kbase + 1];
      o.z = tl[drow * 65 + kbase + 2];
      o.w = tl[drow * 65 + kbase + 3];
      *(ushort4*)(vT + (((size_t)(b * HEADS + h) * HD + drow) * LL) + lt * 64 + s4) = o;
    }
  }
}

// ---------------- Flash attention: wave-pair kv-split, Q=128/block, one residency round ----------
// R5 wall = LDS read pipe: all 8 waves read the whole 16KB tile (8x redundancy). Here wave =
// (half = wave>>2, qg = wave&3): half owns kv rows [half*32, half*32+32), qg owns 32 q-rows
// (2 subtiles of 16). Per wave per tile: 4 kf + 4 vf = 8KB read (HALVED), 16 MFMA, 16 exp2
// (unchanged). sigma maps a kv-half to slots [half*32, half*32+32) = one K=32 PV fragment, so
// the in-register P pack is unchanged with ks fixed = half. Epilogue: one-time cross-pair (w,w+4)
// O/psum reduction through the freed staging LDS. Geometry = R5's proven full-residency shape:
// 672 blocks x 512 thr, 3-stage 48KB, counted vmcnt(2) BEFORE s_barrier, stagger, XCD affinity.
// __launch_bounds__(512,6) caps VGPR at 85 -> 3 blocks/CU (24 waves, 6/SIMD) on the loaded CUs.
__global__ __launch_bounds__(512, 6) void attn_kernel(const unsigned short* __restrict__ qb,
                                                      const unsigned short* __restrict__ kb,
                                                      const unsigned short* __restrict__ vT,
                                                      float* __restrict__ out) {
  __shared__ unsigned short k_lds[3][64 * 64];   // [stage][kv][d], XOR-swizzled chunks (24 KB)
  __shared__ unsigned short v_lds[3][64 * 64];   // [stage][d][slot], XOR-swizzled chunks (24 KB)

  // XCD-affine decode: g&7 = XCD (round-robin dispatch), 84 slots per XCD = 6 bh x 14 qt.
  const int g = blockIdx.x;
  const int xcd = g & 7;
  const int ix = g >> 3;                         // 0..83
  const int qt = ix % 14;                        // 0..13 (qt 13 is a half tile)
  const int bh = xcd * 6 + ix / 14;              // 0..47
  const int h = bh % HEADS;
  const int b = bh / HEADS;
  const int stg = (qt * 2) % 27;                 // KV start tile (stagger)

  const int t = threadIdx.x;
  const int lane = t & 63;
  const int wave = t >> 6;                       // 0..7
  const int m = lane & 15;
  const int quad = lane >> 4;
  const int half = wave >> 2;                    // kv-half this wave computes
  const int qg = wave & 3;                       // q-group (32 q-rows)

  // Q frags (pre-scaled bf16); B-operand layout: lane&15 = q col, ksd*32+quad*8 = d-slice
  bf8 qf[2][2];                                  // [qsub][ksd]
#pragma unroll
  for (int qsub = 0; qsub < 2; ++qsub) {
    int row = qt * 128 + qg * 32 + qsub * 16 + m;
    row = row < LL ? row : LL - 1;               // clamp for the qt==13 half tile
    const size_t qbase = ((size_t)(b * LL + row)) * CC + h * HD;
    qf[qsub][0] = *(const bf8*)(qb + qbase + quad * 8);
    qf[qsub][1] = *(const bf8*)(qb + qbase + 32 + quad * 8);
  }

  // DMA source offsets: chunk cidx = wave*64+lane (512 chunks = one 8KB matrix);
  // row = cidx>>3; src chunk = (cidx&7)^(row&7)  (XOR swizzle, read side matches)
  int koff, voff, ldsb;
  {
    const int cidx = wave * 64 + lane;
    const int row = cidx >> 3;
    const int sc = (cidx & 7) ^ (row & 7);
    koff = row * CC + sc * 8;
    voff = row * LL + sc * 8;
    ldsb = wave * 512;
  }

  const unsigned short* kgb = kb + (size_t)b * LL * CC + h * HD;
  const unsigned short* vgb = vT + ((size_t)(b * HEADS + h) * HD) * LL;

#define ISSUE_TILE(KT, BUF)                                                             \
  {                                                                                     \
    gld16(kgb + (size_t)(KT) * (64 * CC) + koff, &k_lds[BUF][ldsb]);                    \
    gld16(vgb + (KT) * 64 + voff, &v_lds[BUF][ldsb]);                                   \
  }

  // prologue: tiles stg, stg+1 -> stages 0,1 (4 loads/wave in flight)
  ISSUE_TILE(stg, 0)
  {
    int k1 = stg + 1; if (k1 >= 27) k1 -= 27;
    ISSUE_TILE(k1, 1)
  }

  f4 o_acc[4][2] = {};          // [nt(d-group)][qsub]; covers this wave's kv-half only
  float psum[2] = {0.f, 0.f};   // per-lane partial denominator, per q-subtile (kv-half only)

  // body i: physical tile (stg+i)%27 on stage i%3.
  // vmcnt(2): own tile-i loads landed (tile i+1's 2 stay in flight); barrier: ALL waves' tile-i
  // loads landed AND stage (i+2)%3 (read in body i-1) is free; then issue tile i+2 into it.
#define ATTN_BODY(I, STG, WAITN, DOISSUE)                                               \
  {                                                                                     \
    __asm__ volatile("s_waitcnt vmcnt(" #WAITN ")" ::: "memory");                       \
    __builtin_amdgcn_s_barrier();                                                       \
    if (DOISSUE) {                                                                      \
      int ktn = stg + (I) + 2; if (ktn >= 27) ktn -= 27;                                \
      ISSUE_TILE(ktn, ((STG) + 2) % 3)                                                  \
    }                                                                                   \
    f4 s_acc[2][2] = {};  /* [knt(16 kv within half)][qsub] */                          \
    __builtin_amdgcn_s_setprio(1);                                                      \
    _Pragma("unroll")                                                                   \
    for (int knt = 0; knt < 2; ++knt) {                                                 \
      _Pragma("unroll")                                                                 \
      for (int ksd = 0; ksd < 2; ++ksd) {                                               \
        const int cc = ((ksd * 4 + quad) ^ (m & 7)) * 8;                                \
        const bf8 kf = *(const bf8*)&k_lds[STG][(half * 32 + knt * 16 + m) * 64 + cc];  \
        s_acc[knt][0] = __builtin_amdgcn_mfma_f32_16x16x32_bf16(kf, qf[0][ksd], s_acc[knt][0], 0, 0, 0); \
        s_acc[knt][1] = __builtin_amdgcn_mfma_f32_16x16x32_bf16(kf, qf[1][ksd], s_acc[knt][1], 0, 0, 0); \
      }                                                                                 \
    }                                                                                   \
    __builtin_amdgcn_s_setprio(0);                                                      \
    bf8 pf[2];  /* [qsub]; slots half*32 + quad*8 + knt*4 + r -> elem knt*4+r */        \
    _Pragma("unroll")                                                                   \
    for (int qsub = 0; qsub < 2; ++qsub) {                                              \
      union { bf8 v; unsigned int w[4]; } pu;                                           \
      _Pragma("unroll")                                                                 \
      for (int knt = 0; knt < 2; ++knt) {                                               \
        const float p0 = fast_exp2(s_acc[knt][qsub][0]);                                \
        const float p1 = fast_exp2(s_acc[knt][qsub][1]);                                \
        const float p2 = fast_exp2(s_acc[knt][qsub][2]);                                \
        const float p3 = fast_exp2(s_acc[knt][qsub][3]);                                \
        psum[qsub] += (p0 + p1) + (p2 + p3);                                            \
        pu.w[knt * 2 + 0] = (unsigned int)f2bfr(p0) | ((unsigned int)f2bfr(p1) << 16);  \
        pu.w[knt * 2 + 1] = (unsigned int)f2bfr(p2) | ((unsigned int)f2bfr(p3) << 16);  \
      }                                                                                 \
      pf[qsub] = pu.v;                                                                  \
    }                                                                                   \
    __builtin_amdgcn_s_setprio(1);                                                      \
    _Pragma("unroll")                                                                   \
    for (int nt = 0; nt < 4; ++nt) {                                                    \
      const int cc = ((half * 4 + quad) ^ (m & 7)) * 8;                                 \
      const bf8 vf = *(const bf8*)&v_lds[STG][(nt * 16 + m) * 64 + cc];                 \
      o_acc[nt][0] = __builtin_amdgcn_mfma_f32_16x16x32_bf16(vf, pf[0], o_acc[nt][0], 0, 0, 0); \
      o_acc[nt][1] = __builtin_amdgcn_mfma_f32_16x16x32_bf16(vf, pf[1], o_acc[nt][1], 0, 0, 0); \
    }                                                                                   \
    __builtin_amdgcn_s_setprio(0);                                                      \
  }

  // bodies 0..23 (always issue i+2 <= 25), then peeled 24 (issues 26), 25, 26 (drain).
  for (int ip = 0; ip < 8; ++ip) {
    const int i0 = ip * 3;
    ATTN_BODY(i0 + 0, 0, 2, true)
    ATTN_BODY(i0 + 1, 1, 2, true)
    ATTN_BODY(i0 + 2, 2, 2, true)
  }
  ATTN_BODY(24, 0, 2, true)
  ATTN_BODY(25, 1, 2, false)
  ATTN_BODY(26, 2, 0, false)
#undef ATTN_BODY
#undef ISSUE_TILE

  // ---- cross-pair reduction: wave w (half 0) += wave w+4 (half 1), via freed staging LDS ----
  __syncthreads();                                // all waves done reading stage LDS
  {
    float* red = (float*)&k_lds[0][0];            // 48 KB raw scratch; need 36 KB
    const int sid = qg * 64 + lane;               // 0..255, stride 36 floats (144 B, 16B-aligned)
    float* slot = red + sid * 36;
    if (half == 1) {
#pragma unroll
      for (int qsub = 0; qsub < 2; ++qsub) {
#pragma unroll
        for (int nt = 0; nt < 4; ++nt)
          *(f4*)(slot + (qsub * 4 + nt) * 4) = o_acc[nt][qsub];
        slot[32 + qsub] = psum[qsub];
      }
    }
    __syncthreads();
    if (half == 1) return;                        // half-1 waves done
#pragma unroll
    for (int qsub = 0; qsub < 2; ++qsub) {
#pragma unroll
      for (int nt = 0; nt < 4; ++nt) {
        const f4 po = *(const f4*)(slot + (qsub * 4 + nt) * 4);
        o_acc[nt][qsub] += po;
      }
      psum[qsub] += slot[32 + qsub];
    }
  }

  // ---- epilogue: denominator = sum over the 4 quads holding q=m, then out += O^T / l ----
  // o_acc[nt][qsub][r] = O[q = qt*128+qg*32+qsub*16+m][d = nt*16+quad*4+r] -> float4 RMW per nt
#pragma unroll
  for (int qsub = 0; qsub < 2; ++qsub) {
    float s = psum[qsub];
    s += __shfl_xor(s, 16);
    s += __shfl_xor(s, 32);
    const float inv = 1.0f / s;
    const int rowq = qt * 128 + qg * 32 + qsub * 16 + m;
    if (rowq < LL) {
      float* op = out + ((size_t)b * LL + rowq) * CC + h * HD + quad * 4;
#pragma unroll
      for (int nt = 0; nt < 4; ++nt) {
        float4 o4 = *(float4*)&op[nt * 16];
        o4.x += o_acc[nt][qsub][0] * inv;
        o4.y += o_acc[nt][qsub][1] * inv;
        o4.z += o_acc[nt][qsub][2] * inv;
        o4.w += o_acc[nt][qsub][3] * inv;
        *(float4*)&op[nt * 16] = o4;
      }
    }
  }
}

extern "C" void kernel_launch(void* const* d_in, const int* in_sizes, int n_in,
                              void* d_out, int out_size, void* d_ws, size_t ws_size,
                              hipStream_t stream) {
  (void)in_sizes; (void)n_in; (void)ws_size; (void)out_size;
  const float* qkv = (const float*)d_in[0];
  const float* lepe_w = (const float*)d_in[1];
  const float* lepe_b = (const float*)d_in[2];
  float* out = (float*)d_out;

  const size_t NE = (size_t)BATCH * LL * CC;
  unsigned short* qb = (unsigned short*)d_ws;
  unsigned short* kb = qb + NE;
  unsigned short* vT = kb + NE;  // 3*NE*2 B ~ 31.9 MB of ws

  combined_kernel<<<dim3(NLEPE + NPREP), 256, 0, stream>>>(qkv, lepe_w, lepe_b, qb, kb, vT, out);
  attn_kernel<<<dim3(672), 512, 0, stream>>>(qb, kb, vT, out);
}

// Round 8
// 181.060 us; speedup vs baseline: 2.0486x; 2.0486x over previous
//
#include <hip/hip_runtime.h>

#define RR 12
#define LL 1728
#define CC 768
#define HEADS 12
#define HD 64
#define BATCH 4

typedef __attribute__((ext_vector_type(8))) short bf8;   // 8 x bf16
typedef __attribute__((ext_vector_type(4))) float f4;    // 4 x fp32

__device__ inline unsigned short f2bf(float x) {         // RNE-ish
  unsigned int u = __float_as_uint(x);
  return (unsigned short)((u + 0x7FFFu + ((u >> 16) & 1u)) >> 16);
}
__device__ inline unsigned short f2bfr(float x) {        // round-half-up (cheap)
  return (unsigned short)((__float_as_uint(x) + 0x8000u) >> 16);
}

__device__ inline float fast_exp2(float x) {
#if __has_builtin(__builtin_amdgcn_exp2f)
  return __builtin_amdgcn_exp2f(x);
#else
  return exp2f(x);
#endif
}

// async 16B global->LDS (wave-uniform LDS base + lane*16)
__device__ inline void gld16(const unsigned short* g, unsigned short* l) {
  __builtin_amdgcn_global_load_lds((const __attribute__((address_space(1))) unsigned int*)g,
                                   (__attribute__((address_space(3))) unsigned int*)l, 16, 0, 0);
}

#define QSCALE 0.1803368801111244f  /* 0.125 * log2(e): folds softmax base-2 conversion in */

#define NLEPE 5184  /* 432 lines*xgroups x 3 ctiles x 4 batch */
#define NPREP 1296  /* 27 ltiles x 12 heads x 4 batch */

// ---------------- combined prep + lepe (block-uniform partition; 1 launch instead of 3) ------------
// blocks [0, NLEPE): LePE depthwise conv (4 x-positions per block — R0-proven lean shape).
// blocks [NLEPE, NLEPE+NPREP): q,k -> bf16 (q pre-scaled by QSCALE); v -> vT[b][h][d][sigma(k)].
// Slot permutation (for swapped-QK in-register P):
//   sigma(k) with k = nt*16 + quad*4 + r  ->  slot = (nt>>1)*32 + quad*8 + (nt&1)*4 + r
// Note sigma maps kv rows 0..31 -> slots 0..31 and rows 32..63 -> slots 32..63: a kv-HALF of the
// tile is exactly one K=32 PV fragment — this is what the attn kernel's wave-pair kv-split uses.
__global__ __launch_bounds__(256) void combined_kernel(const float* __restrict__ qkv,
                                                       const float* __restrict__ w,
                                                       const float* __restrict__ bias,
                                                       unsigned short* __restrict__ qb,
                                                       unsigned short* __restrict__ kb,
                                                       unsigned short* __restrict__ vT,
                                                       float* __restrict__ out) {
  __shared__ __align__(16) unsigned char smem[27648];  // union: lepe w-stage 27 KB / prep tl 8.3 KB
  const int bid = blockIdx.x;
  const int t = threadIdx.x;

  if (bid < NLEPE) {
    // ================= LePE =================
    const int xg = (bid % 3) * 4;            // x0 in {0,4,8}
    const int line = (bid / 3) % 144;        // z*12+y
    const int ct = (bid / 432) % 3;          // c-tile
    const int b = bid / 1296;
    const int z = line / RR;
    const int y = line % RR;
    const int c0 = ct * 256;
    const int c = c0 + t;
    float* w_lds = (float*)smem;

    // coalesced stage of w[c0*27 .. (c0+256)*27) as float4 (6912 floats)
    {
      const float* wsrc = w + (size_t)c0 * 27;
#pragma unroll
      for (int i = 0; i < 7; ++i) {
        const int idx = i * 256 + t;         // float4 index, 0..1727
        if (idx < 1728) *(float4*)&w_lds[idx * 4] = *(const float4*)&wsrc[idx * 4];
      }
    }
    __syncthreads();
    float wreg[27];
#pragma unroll
    for (int j = 0; j < 27; ++j) wreg[j] = w_lds[t * 27 + j];  // stride 27 ⊥ 32: 2-way, free

    const float* vb = qkv + ((size_t)(2 * BATCH + b)) * LL * CC + c;
    const float bv = bias[c];
    float acc[4] = {bv, bv, bv, bv};

#pragma unroll
    for (int dz = -1; dz <= 1; ++dz) {
#pragma unroll
      for (int dy = -1; dy <= 1; ++dy) {
        const int zz = z + dz, yy = y + dy;
        const bool lineok = ((unsigned)zz < RR) & ((unsigned)yy < RR);  // block-uniform
        const int base = (zz * RR + yy) * RR;
        float v6[6];                        // x-positions xg-1 .. xg+4, masked address-safe loads
#pragma unroll
        for (int p = 0; p < 6; ++p) {
          const int xx = xg - 1 + p;
          const bool ok = lineok & ((unsigned)xx < RR);
          const int lp = ok ? base + xx : 0;
          const float vv = vb[(size_t)lp * CC];
          v6[p] = ok ? vv : 0.f;
        }
        const int jb = ((dz + 1) * 3 + (dy + 1)) * 3;
        const float wL = wreg[jb], wC = wreg[jb + 1], wR = wreg[jb + 2];
#pragma unroll
        for (int i = 0; i < 4; ++i)
          acc[i] += wL * v6[i] + wC * v6[i + 1] + wR * v6[i + 2];
      }
    }
    const size_t obase = ((size_t)b * LL + line * RR + xg) * CC + c;
#pragma unroll
    for (int i = 0; i < 4; ++i) out[obase + (size_t)i * CC] = acc[i];

  } else {
    // ================= prep =================
    const int p = bid - NLEPE;
    const int lt = p % 27;
    const int h = (p / 27) % HEADS;
    const int b = p / (27 * HEADS);
    unsigned short* tl = (unsigned short*)smem;  // [d][l_local], stride 65

    // ---- q/k bf16 conversion for rows lt*64.., cols h*64.. ----
    {
      const int r0 = t >> 4;             // 0..15
      const int c4 = (t & 15) * 4;       // 0..60
#pragma unroll
      for (int pi = 0; pi < 4; ++pi) {
        const int row = lt * 64 + pi * 16 + r0;
        const size_t off = ((size_t)b * LL + row) * CC + h * HD + c4;
        const float4 qv = *(const float4*)(qkv + off);
        ushort4 oq;
        oq.x = f2bf(qv.x * QSCALE); oq.y = f2bf(qv.y * QSCALE);
        oq.z = f2bf(qv.z * QSCALE); oq.w = f2bf(qv.w * QSCALE);
        *(ushort4*)(qb + off) = oq;
        const float4 kv = *(const float4*)(qkv + (size_t)BATCH * LL * CC + off);
        ushort4 ok;
        ok.x = f2bf(kv.x); ok.y = f2bf(kv.y); ok.z = f2bf(kv.z); ok.w = f2bf(kv.w);
        *(ushort4*)(kb + off) = ok;
      }
    }

    // ---- vT with slot permutation ----
    const float* vsrc = qkv + ((size_t)(2 * BATCH + b)) * LL * CC;
#pragma unroll
    for (int it = 0; it < 4; ++it) {
      const int idx = it * 256 + t;
      const int lrow = idx >> 4;
      const int c4 = (idx & 15) * 4;
      const float4 vv = *(const float4*)(vsrc + (size_t)(lt * 64 + lrow) * CC + h * HD + c4);
      tl[(c4 + 0) * 65 + lrow] = f2bf(vv.x);
      tl[(c4 + 1) * 65 + lrow] = f2bf(vv.y);
      tl[(c4 + 2) * 65 + lrow] = f2bf(vv.z);
      tl[(c4 + 3) * 65 + lrow] = f2bf(vv.w);
    }
    __syncthreads();
#pragma unroll
    for (int it = 0; it < 4; ++it) {
      const int idx = it * 256 + t;
      const int drow = idx >> 4;
      const int u = idx & 15;            // slot group: s4 = u*4
      const int s4 = u * 4;
      // slots s4..s4+3 hold physical kv rows kbase..kbase+3 (consecutive):
      //   kbase = ((u>>3)*2 + (u&1))*16 + ((u>>1)&3)*4
      const int kbase = (((u >> 3) * 2 + (u & 1)) << 4) + (((u >> 1) & 3) << 2);
      ushort4 o;
      o.x = tl[drow * 65 + kbase + 0];
      o.y = tl[drow * 65 + kbase + 1];
      o.z = tl[drow * 65 + kbase + 2];
      o.w = tl[drow * 65 + kbase + 3];
      *(ushort4*)(vT + (((size_t)(b * HEADS + h) * HD + drow) * LL) + lt * 64 + s4) = o;
    }
  }
}

// ---------------- Flash attention: wave-pair kv-split, Q=128/block, one residency round ----------
// Same structure as R7 (which PASSED correctness but spilled ~45 VGPRs to scratch -> 1GB HBM
// traffic). Root cause: hipcc's __launch_bounds__ 2nd arg acts as min BLOCKS/CU (CUDA semantics):
// (512,6)->48 waves/CU->VGPR cap 42 (measured 40); (512,4)->cap 64 (measured 64, R6).
// FIX: __launch_bounds__(512, 3) -> 24 waves/CU -> VGPR cap ~85, which fits this body's ~85-reg
// peak (o_acc 32 + qf 16 + addr ~14 + transient s_acc/pf). 3 blocks x 48KB LDS = 144 <= 160KB,
// 672 blocks <= 768 slots -> one residency round preserved.
// Wave = (half = wave>>2, qg = wave&3): half owns kv rows [half*32,+32), qg owns 32 q-rows.
// Per wave per tile: 4 kf + 4 vf ds_read_b128 (HALF of R5), 16 MFMA, 16 exp2. sigma maps a
// kv-half to slots [half*32,+32) = one K=32 PV fragment -> in-register P, ks fixed = half.
// Epilogue: one-time cross-pair (w, w+4) O/psum reduction through freed staging LDS.
__global__ __launch_bounds__(512, 3) void attn_kernel(const unsigned short* __restrict__ qb,
                                                      const unsigned short* __restrict__ kb,
                                                      const unsigned short* __restrict__ vT,
                                                      float* __restrict__ out) {
  __shared__ unsigned short k_lds[3][64 * 64];   // [stage][kv][d], XOR-swizzled chunks (24 KB)
  __shared__ unsigned short v_lds[3][64 * 64];   // [stage][d][slot], XOR-swizzled chunks (24 KB)

  // XCD-affine decode: g&7 = XCD (round-robin dispatch), 84 slots per XCD = 6 bh x 14 qt.
  const int g = blockIdx.x;
  const int xcd = g & 7;
  const int ix = g >> 3;                         // 0..83
  const int qt = ix % 14;                        // 0..13 (qt 13 is a half tile)
  const int bh = xcd * 6 + ix / 14;              // 0..47
  const int h = bh % HEADS;
  const int b = bh / HEADS;
  const int stg = (qt * 2) % 27;                 // KV start tile (stagger)

  const int t = threadIdx.x;
  const int lane = t & 63;
  const int wave = t >> 6;                       // 0..7
  const int m = lane & 15;
  const int quad = lane >> 4;
  const int half = wave >> 2;                    // kv-half this wave computes
  const int qg = wave & 3;                       // q-group (32 q-rows)

  // Q frags (pre-scaled bf16); B-operand layout: lane&15 = q col, ksd*32+quad*8 = d-slice
  bf8 qf[2][2];                                  // [qsub][ksd]
#pragma unroll
  for (int qsub = 0; qsub < 2; ++qsub) {
    int row = qt * 128 + qg * 32 + qsub * 16 + m;
    row = row < LL ? row : LL - 1;               // clamp for the qt==13 half tile
    const size_t qbase = ((size_t)(b * LL + row)) * CC + h * HD;
    qf[qsub][0] = *(const bf8*)(qb + qbase + quad * 8);
    qf[qsub][1] = *(const bf8*)(qb + qbase + 32 + quad * 8);
  }

  // DMA source offsets: chunk cidx = wave*64+lane (512 chunks = one 8KB matrix);
  // row = cidx>>3; src chunk = (cidx&7)^(row&7)  (XOR swizzle, read side matches)
  int koff, voff, ldsb;
  {
    const int cidx = wave * 64 + lane;
    const int row = cidx >> 3;
    const int sc = (cidx & 7) ^ (row & 7);
    koff = row * CC + sc * 8;
    voff = row * LL + sc * 8;
    ldsb = wave * 512;
  }

  const unsigned short* kgb = kb + (size_t)b * LL * CC + h * HD;
  const unsigned short* vgb = vT + ((size_t)(b * HEADS + h) * HD) * LL;

#define ISSUE_TILE(KT, BUF)                                                             \
  {                                                                                     \
    gld16(kgb + (size_t)(KT) * (64 * CC) + koff, &k_lds[BUF][ldsb]);                    \
    gld16(vgb + (KT) * 64 + voff, &v_lds[BUF][ldsb]);                                   \
  }

  // prologue: tiles stg, stg+1 -> stages 0,1 (4 loads/wave in flight)
  ISSUE_TILE(stg, 0)
  {
    int k1 = stg + 1; if (k1 >= 27) k1 -= 27;
    ISSUE_TILE(k1, 1)
  }

  f4 o_acc[4][2] = {};          // [nt(d-group)][qsub]; covers this wave's kv-half only
  float psum[2] = {0.f, 0.f};   // per-lane partial denominator, per q-subtile (kv-half only)

  // body i: physical tile (stg+i)%27 on stage i%3.
  // vmcnt(2): own tile-i loads landed (tile i+1's 2 stay in flight); barrier: ALL waves' tile-i
  // loads landed AND stage (i+2)%3 (read in body i-1) is free; then issue tile i+2 into it.
#define ATTN_BODY(I, STG, WAITN, DOISSUE)                                               \
  {                                                                                     \
    __asm__ volatile("s_waitcnt vmcnt(" #WAITN ")" ::: "memory");                       \
    __builtin_amdgcn_s_barrier();                                                       \
    if (DOISSUE) {                                                                      \
      int ktn = stg + (I) + 2; if (ktn >= 27) ktn -= 27;                                \
      ISSUE_TILE(ktn, ((STG) + 2) % 3)                                                  \
    }                                                                                   \
    f4 s_acc[2][2] = {};  /* [knt(16 kv within half)][qsub] */                          \
    __builtin_amdgcn_s_setprio(1);                                                      \
    _Pragma("unroll")                                                                   \
    for (int knt = 0; knt < 2; ++knt) {                                                 \
      _Pragma("unroll")                                                                 \
      for (int ksd = 0; ksd < 2; ++ksd) {                                               \
        const int cc = ((ksd * 4 + quad) ^ (m & 7)) * 8;                                \
        const bf8 kf = *(const bf8*)&k_lds[STG][(half * 32 + knt * 16 + m) * 64 + cc];  \
        s_acc[knt][0] = __builtin_amdgcn_mfma_f32_16x16x32_bf16(kf, qf[0][ksd], s_acc[knt][0], 0, 0, 0); \
        s_acc[knt][1] = __builtin_amdgcn_mfma_f32_16x16x32_bf16(kf, qf[1][ksd], s_acc[knt][1], 0, 0, 0); \
      }                                                                                 \
    }                                                                                   \
    __builtin_amdgcn_s_setprio(0);                                                      \
    bf8 pf[2];  /* [qsub]; slots half*32 + quad*8 + knt*4 + r -> elem knt*4+r */        \
    _Pragma("unroll")                                                                   \
    for (int qsub = 0; qsub < 2; ++qsub) {                                              \
      union { bf8 v; unsigned int w[4]; } pu;                                           \
      _Pragma("unroll")                                                                 \
      for (int knt = 0; knt < 2; ++knt) {                                               \
        const float p0 = fast_exp2(s_acc[knt][qsub][0]);                                \
        const float p1 = fast_exp2(s_acc[knt][qsub][1]);                                \
        const float p2 = fast_exp2(s_acc[knt][qsub][2]);                                \
        const float p3 = fast_exp2(s_acc[knt][qsub][3]);                                \
        psum[qsub] += (p0 + p1) + (p2 + p3);                                            \
        pu.w[knt * 2 + 0] = (unsigned int)f2bfr(p0) | ((unsigned int)f2bfr(p1) << 16);  \
        pu.w[knt * 2 + 1] = (unsigned int)f2bfr(p2) | ((unsigned int)f2bfr(p3) << 16);  \
      }                                                                                 \
      pf[qsub] = pu.v;                                                                  \
    }                                                                                   \
    __builtin_amdgcn_s_setprio(1);                                                      \
    _Pragma("unroll")                                                                   \
    for (int nt = 0; nt < 4; ++nt) {                                                    \
      const int cc = ((half * 4 + quad) ^ (m & 7)) * 8;                                 \
      const bf8 vf = *(const bf8*)&v_lds[STG][(nt * 16 + m) * 64 + cc];                 \
      o_acc[nt][0] = __builtin_amdgcn_mfma_f32_16x16x32_bf16(vf, pf[0], o_acc[nt][0], 0, 0, 0); \
      o_acc[nt][1] = __builtin_amdgcn_mfma_f32_16x16x32_bf16(vf, pf[1], o_acc[nt][1], 0, 0, 0); \
    }                                                                                   \
    __builtin_amdgcn_s_setprio(0);                                                      \
  }

  // bodies 0..23 (always issue i+2 <= 25), then peeled 24 (issues 26), 25, 26 (drain).
  for (int ip = 0; ip < 8; ++ip) {
    const int i0 = ip * 3;
    ATTN_BODY(i0 + 0, 0, 2, true)
    ATTN_BODY(i0 + 1, 1, 2, true)
    ATTN_BODY(i0 + 2, 2, 2, true)
  }
  ATTN_BODY(24, 0, 2, true)
  ATTN_BODY(25, 1, 2, false)
  ATTN_BODY(26, 2, 0, false)
#undef ATTN_BODY
#undef ISSUE_TILE

  // ---- cross-pair reduction: wave w (half 0) += wave w+4 (half 1), via freed staging LDS ----
  __syncthreads();                                // all waves done reading stage LDS
  {
    float* red = (float*)&k_lds[0][0];            // 48 KB raw scratch; need 36 KB
    const int sid = qg * 64 + lane;               // 0..255, stride 36 floats (144 B, 16B-aligned)
    float* slot = red + sid * 36;
    if (half == 1) {
#pragma unroll
      for (int qsub = 0; qsub < 2; ++qsub) {
#pragma unroll
        for (int nt = 0; nt < 4; ++nt)
          *(f4*)(slot + (qsub * 4 + nt) * 4) = o_acc[nt][qsub];
        slot[32 + qsub] = psum[qsub];
      }
    }
    __syncthreads();
    if (half == 1) return;                        // half-1 waves done
#pragma unroll
    for (int qsub = 0; qsub < 2; ++qsub) {
#pragma unroll
      for (int nt = 0; nt < 4; ++nt) {
        const f4 po = *(const f4*)(slot + (qsub * 4 + nt) * 4);
        o_acc[nt][qsub] += po;
      }
      psum[qsub] += slot[32 + qsub];
    }
  }

  // ---- epilogue: denominator = sum over the 4 quads holding q=m, then out += O^T / l ----
  // o_acc[nt][qsub][r] = O[q = qt*128+qg*32+qsub*16+m][d = nt*16+quad*4+r] -> float4 RMW per nt
#pragma unroll
  for (int qsub = 0; qsub < 2; ++qsub) {
    float s = psum[qsub];
    s += __shfl_xor(s, 16);
    s += __shfl_xor(s, 32);
    const float inv = 1.0f / s;
    const int rowq = qt * 128 + qg * 32 + qsub * 16 + m;
    if (rowq < LL) {
      float* op = out + ((size_t)b * LL + rowq) * CC + h * HD + quad * 4;
#pragma unroll
      for (int nt = 0; nt < 4; ++nt) {
        float4 o4 = *(float4*)&op[nt * 16];
        o4.x += o_acc[nt][qsub][0] * inv;
        o4.y += o_acc[nt][qsub][1] * inv;
        o4.z += o_acc[nt][qsub][2] * inv;
        o4.w += o_acc[nt][qsub][3] * inv;
        *(float4*)&op[nt * 16] = o4;
      }
    }
  }
}

extern "C" void kernel_launch(void* const* d_in, const int* in_sizes, int n_in,
                              void* d_out, int out_size, void* d_ws, size_t ws_size,
                              hipStream_t stream) {
  (void)in_sizes; (void)n_in; (void)ws_size; (void)out_size;
  const float* qkv = (const float*)d_in[0];
  const float* lepe_w = (const float*)d_in[1];
  const float* lepe_b = (const float*)d_in[2];
  float* out = (float*)d_out;

  const size_t NE = (size_t)BATCH * LL * CC;
  unsigned short* qb = (unsigned short*)d_ws;
  unsigned short* kb = qb + NE;
  unsigned short* vT = kb + NE;  // 3*NE*2 B ~ 31.9 MB of ws

  combined_kernel<<<dim3(NLEPE + NPREP), 256, 0, stream>>>(qkv, lepe_w, lepe_b, qb, kb, vT, out);
  attn_kernel<<<dim3(672), 512, 0, stream>>>(qb, kb, vT, out);
}

// Round 10
// 168.740 us; speedup vs baseline: 2.1982x; 1.0730x over previous
//
#include <hip/hip_runtime.h>

#define RR 12
#define LL 1728
#define CC 768
#define HEADS 12
#define HD 64
#define BATCH 4

typedef __attribute__((ext_vector_type(8))) short bf8;   // 8 x bf16
typedef __attribute__((ext_vector_type(4))) float f4;    // 4 x fp32

__device__ inline unsigned short f2bf(float x) {         // RNE-ish
  unsigned int u = __float_as_uint(x);
  return (unsigned short)((u + 0x7FFFu + ((u >> 16) & 1u)) >> 16);
}
__device__ inline unsigned short f2bfr(float x) {        // round-half-up (cheap)
  return (unsigned short)((__float_as_uint(x) + 0x8000u) >> 16);
}

__device__ inline float fast_exp2(float x) {
#if __has_builtin(__builtin_amdgcn_exp2f)
  return __builtin_amdgcn_exp2f(x);
#else
  return exp2f(x);
#endif
}

// async 16B global->LDS (wave-uniform LDS base + lane*16)
__device__ inline void gld16(const unsigned short* g, unsigned short* l) {
  __builtin_amdgcn_global_load_lds((const __attribute__((address_space(1))) unsigned int*)g,
                                   (__attribute__((address_space(3))) unsigned int*)l, 16, 0, 0);
}

#define QSCALE 0.1803368801111244f  /* 0.125 * log2(e): folds softmax base-2 conversion in */

#define NLEPE 1296  /* 3 xg x 3 yg x 12 z x 3 ctiles x 4 batch (4x4 y,x patch per block) */
#define NPREP 1296  /* 27 ltiles x 12 heads x 4 batch */

// ---------------- combined prep + lepe (block-uniform partition; 1 launch instead of 3) ------------
// blocks [0, NLEPE): LePE depthwise conv as 4x4 (y,x) patches with z-plane accumulation:
//   loop the 3 z-planes; per plane load a 6x6 (y,x) halo window (36 masked loads) and accumulate
//   the 9 in-plane taps into 16 accs. Per 16 outputs: 108 v-loads (vs 216 in the 4-x-block shape)
//   and ONE 27KB w-stage (vs 4) -> w L2 traffic 140->35MB, LePE blocks 5184->1296.
// blocks [NLEPE, NLEPE+NPREP): q,k -> bf16 (q pre-scaled by QSCALE); v -> vT[b][h][d][sigma(k)].
// Slot permutation (for swapped-QK in-register P):
//   sigma(k) with k = nt*16 + quad*4 + r  ->  slot = (nt>>1)*32 + quad*8 + (nt&1)*4 + r
// Note sigma maps kv rows 0..31 -> slots 0..31 and rows 32..63 -> slots 32..63: a kv-HALF of the
// tile is exactly one K=32 PV fragment — this is what the attn kernel's wave-pair kv-split uses.
__global__ __launch_bounds__(256) void combined_kernel(const float* __restrict__ qkv,
                                                       const float* __restrict__ w,
                                                       const float* __restrict__ bias,
                                                       unsigned short* __restrict__ qb,
                                                       unsigned short* __restrict__ kb,
                                                       unsigned short* __restrict__ vT,
                                                       float* __restrict__ out) {
  __shared__ __align__(16) unsigned char smem[27648];  // union: lepe w-stage 27 KB / prep tl 8.3 KB
  const int bid = blockIdx.x;
  const int t = threadIdx.x;

  if (bid < NLEPE) {
    // ================= LePE: 4x4 (y,x) patch, z-plane accumulation =================
    const int xg = (bid % 3) * 4;            // x0 in {0,4,8}
    const int yg = ((bid / 3) % 3) * 4;      // y0 in {0,4,8}
    const int z = (bid / 9) % RR;
    const int ct = (bid / 108) % 3;          // c-tile
    const int b = bid / 324;
    const int c0 = ct * 256;
    const int c = c0 + t;
    float* w_lds = (float*)smem;

    // coalesced stage of w[c0*27 .. (c0+256)*27) as float4 (6912 floats)
    {
      const float* wsrc = w + (size_t)c0 * 27;
#pragma unroll
      for (int i = 0; i < 7; ++i) {
        const int idx = i * 256 + t;         // float4 index, 0..1727
        if (idx < 1728) *(float4*)&w_lds[idx * 4] = *(const float4*)&wsrc[idx * 4];
      }
    }
    __syncthreads();
    float wreg[27];
#pragma unroll
    for (int j = 0; j < 27; ++j) wreg[j] = w_lds[t * 27 + j];  // stride 27 ⊥ 32: 2-way, free

    const float* vb = qkv + ((size_t)(2 * BATCH + b)) * LL * CC + c;
    const float bv = bias[c];
    float acc[4][4];
#pragma unroll
    for (int yy = 0; yy < 4; ++yy)
#pragma unroll
      for (int xx = 0; xx < 4; ++xx) acc[yy][xx] = bv;

#pragma unroll
    for (int dzp = 0; dzp < 3; ++dzp) {
      const int zp = z + dzp - 1;
      const bool zok = (unsigned)zp < RR;    // block-uniform
      // 6x6 halo window: y' = yg-1+wy, x' = xg-1+wx; masked address-safe loads
      float vwin[6][6];
#pragma unroll
      for (int wy = 0; wy < 6; ++wy) {
        const int yp = yg - 1 + wy;
        const bool yok = zok & ((unsigned)yp < RR);
        const int rowbase = (zp * RR + yp) * RR;
#pragma unroll
        for (int wx = 0; wx < 6; ++wx) {
          const int xp = xg - 1 + wx;
          const bool ok = yok & ((unsigned)xp < RR);
          const int lp = ok ? rowbase + xp : 0;
          const float vv = vb[(size_t)lp * CC];
          vwin[wy][wx] = ok ? vv : 0.f;
        }
      }
      // accumulate the 9 in-plane taps
#pragma unroll
      for (int dy = 0; dy < 3; ++dy) {
        const float w0 = wreg[dzp * 9 + dy * 3 + 0];
        const float w1 = wreg[dzp * 9 + dy * 3 + 1];
        const float w2 = wreg[dzp * 9 + dy * 3 + 2];
#pragma unroll
        for (int yy = 0; yy < 4; ++yy) {
#pragma unroll
          for (int xx = 0; xx < 4; ++xx)
            acc[yy][xx] += w0 * vwin[yy + dy][xx] + w1 * vwin[yy + dy][xx + 1] +
                           w2 * vwin[yy + dy][xx + 2];
        }
      }
    }
#pragma unroll
    for (int yy = 0; yy < 4; ++yy) {
      const size_t obase = ((size_t)b * LL + (z * RR + yg + yy) * RR + xg) * CC + c;
#pragma unroll
      for (int xx = 0; xx < 4; ++xx) out[obase + (size_t)xx * CC] = acc[yy][xx];
    }

  } else {
    // ================= prep =================
    const int p = bid - NLEPE;
    const int lt = p % 27;
    const int h = (p / 27) % HEADS;
    const int b = p / (27 * HEADS);
    unsigned short* tl = (unsigned short*)smem;  // [d][l_local], stride 65

    // ---- q/k bf16 conversion for rows lt*64.., cols h*64.. ----
    {
      const int r0 = t >> 4;             // 0..15
      const int c4 = (t & 15) * 4;       // 0..60
#pragma unroll
      for (int pi = 0; pi < 4; ++pi) {
        const int row = lt * 64 + pi * 16 + r0;
        const size_t off = ((size_t)b * LL + row) * CC + h * HD + c4;
        const float4 qv = *(const float4*)(qkv + off);
        ushort4 oq;
        oq.x = f2bf(qv.x * QSCALE); oq.y = f2bf(qv.y * QSCALE);
        oq.z = f2bf(qv.z * QSCALE); oq.w = f2bf(qv.w * QSCALE);
        *(ushort4*)(qb + off) = oq;
        const float4 kv = *(const float4*)(qkv + (size_t)BATCH * LL * CC + off);
        ushort4 ok;
        ok.x = f2bf(kv.x); ok.y = f2bf(kv.y); ok.z = f2bf(kv.z); ok.w = f2bf(kv.w);
        *(ushort4*)(kb + off) = ok;
      }
    }

    // ---- vT with slot permutation ----
    const float* vsrc = qkv + ((size_t)(2 * BATCH + b)) * LL * CC;
#pragma unroll
    for (int it = 0; it < 4; ++it) {
      const int idx = it * 256 + t;
      const int lrow = idx >> 4;
      const int c4 = (idx & 15) * 4;
      const float4 vv = *(const float4*)(vsrc + (size_t)(lt * 64 + lrow) * CC + h * HD + c4);
      tl[(c4 + 0) * 65 + lrow] = f2bf(vv.x);
      tl[(c4 + 1) * 65 + lrow] = f2bf(vv.y);
      tl[(c4 + 2) * 65 + lrow] = f2bf(vv.z);
      tl[(c4 + 3) * 65 + lrow] = f2bf(vv.w);
    }
    __syncthreads();
#pragma unroll
    for (int it = 0; it < 4; ++it) {
      const int idx = it * 256 + t;
      const int drow = idx >> 4;
      const int u = idx & 15;            // slot group: s4 = u*4
      const int s4 = u * 4;
      // slots s4..s4+3 hold physical kv rows kbase..kbase+3 (consecutive):
      //   kbase = ((u>>3)*2 + (u&1))*16 + ((u>>1)&3)*4
      const int kbase = (((u >> 3) * 2 + (u & 1)) << 4) + (((u >> 1) & 3) << 2);
      ushort4 o;
      o.x = tl[drow * 65 + kbase + 0];
      o.y = tl[drow * 65 + kbase + 1];
      o.z = tl[drow * 65 + kbase + 2];
      o.w = tl[drow * 65 + kbase + 3];
      *(ushort4*)(vT + (((size_t)(b * HEADS + h) * HD + drow) * LL) + lt * 64 + s4) = o;
    }
  }
}

// ---------------- Flash attention: wave-pair kv-split, Q=128/block, one residency round ----------
// R8-proven: 61.6us, VGPR 60, no spill. (Unchanged — R9 targets combined_kernel.)
// Wave = (half = wave>>2, qg = wave&3): half owns kv rows [half*32,+32), qg owns 32 q-rows.
// Per wave per tile: 4 kf + 4 vf ds_read_b128, 16 MFMA, 16 exp2. sigma maps a kv-half to slots
// [half*32,+32) = one K=32 PV fragment -> in-register P, ks fixed = half. Epilogue: one-time
// cross-pair (w, w+4) O/psum reduction through freed staging LDS.
// __launch_bounds__(512,3): 2nd arg = min BLOCKS/CU (CUDA semantics) -> VGPR cap ~85.
__global__ __launch_bounds__(512, 3) void attn_kernel(const unsigned short* __restrict__ qb,
                                                      const unsigned short* __restrict__ kb,
                                                      const unsigned short* __restrict__ vT,
                                                      float* __restrict__ out) {
  __shared__ unsigned short k_lds[3][64 * 64];   // [stage][kv][d], XOR-swizzled chunks (24 KB)
  __shared__ unsigned short v_lds[3][64 * 64];   // [stage][d][slot], XOR-swizzled chunks (24 KB)

  // XCD-affine decode: g&7 = XCD (round-robin dispatch), 84 slots per XCD = 6 bh x 14 qt.
  const int g = blockIdx.x;
  const int xcd = g & 7;
  const int ix = g >> 3;                         // 0..83
  const int qt = ix % 14;                        // 0..13 (qt 13 is a half tile)
  const int bh = xcd * 6 + ix / 14;              // 0..47
  const int h = bh % HEADS;
  const int b = bh / HEADS;
  const int stg = (qt * 2) % 27;                 // KV start tile (stagger)

  const int t = threadIdx.x;
  const int lane = t & 63;
  const int wave = t >> 6;                       // 0..7
  const int m = lane & 15;
  const int quad = lane >> 4;
  const int half = wave >> 2;                    // kv-half this wave computes
  const int qg = wave & 3;                       // q-group (32 q-rows)

  // Q frags (pre-scaled bf16); B-operand layout: lane&15 = q col, ksd*32+quad*8 = d-slice
  bf8 qf[2][2];                                  // [qsub][ksd]
#pragma unroll
  for (int qsub = 0; qsub < 2; ++qsub) {
    int row = qt * 128 + qg * 32 + qsub * 16 + m;
    row = row < LL ? row : LL - 1;               // clamp for the qt==13 half tile
    const size_t qbase = ((size_t)(b * LL + row)) * CC + h * HD;
    qf[qsub][0] = *(const bf8*)(qb + qbase + quad * 8);
    qf[qsub][1] = *(const bf8*)(qb + qbase + 32 + quad * 8);
  }

  // DMA source offsets: chunk cidx = wave*64+lane (512 chunks = one 8KB matrix);
  // row = cidx>>3; src chunk = (cidx&7)^(row&7)  (XOR swizzle, read side matches)
  int koff, voff, ldsb;
  {
    const int cidx = wave * 64 + lane;
    const int row = cidx >> 3;
    const int sc = (cidx & 7) ^ (row & 7);
    koff = row * CC + sc * 8;
    voff = row * LL + sc * 8;
    ldsb = wave * 512;
  }

  const unsigned short* kgb = kb + (size_t)b * LL * CC + h * HD;
  const unsigned short* vgb = vT + ((size_t)(b * HEADS + h) * HD) * LL;

#define ISSUE_TILE(KT, BUF)                                                             \
  {                                                                                     \
    gld16(kgb + (size_t)(KT) * (64 * CC) + koff, &k_lds[BUF][ldsb]);                    \
    gld16(vgb + (KT) * 64 + voff, &v_lds[BUF][ldsb]);                                   \
  }

  // prologue: tiles stg, stg+1 -> stages 0,1 (4 loads/wave in flight)
  ISSUE_TILE(stg, 0)
  {
    int k1 = stg + 1; if (k1 >= 27) k1 -= 27;
    ISSUE_TILE(k1, 1)
  }

  f4 o_acc[4][2] = {};          // [nt(d-group)][qsub]; covers this wave's kv-half only
  float psum[2] = {0.f, 0.f};   // per-lane partial denominator, per q-subtile (kv-half only)

  // body i: physical tile (stg+i)%27 on stage i%3.
  // vmcnt(2): own tile-i loads landed (tile i+1's 2 stay in flight); barrier: ALL waves' tile-i
  // loads landed AND stage (i+2)%3 (read in body i-1) is free; then issue tile i+2 into it.
#define ATTN_BODY(I, STG, WAITN, DOISSUE)                                               \
  {                                                                                     \
    __asm__ volatile("s_waitcnt vmcnt(" #WAITN ")" ::: "memory");                       \
    __builtin_amdgcn_s_barrier();                                                       \
    if (DOISSUE) {                                                                      \
      int ktn = stg + (I) + 2; if (ktn >= 27) ktn -= 27;                                \
      ISSUE_TILE(ktn, ((STG) + 2) % 3)                                                  \
    }                                                                                   \
    f4 s_acc[2][2] = {};  /* [knt(16 kv within half)][qsub] */                          \
    __builtin_amdgcn_s_setprio(1);                                                      \
    _Pragma("unroll")                                                                   \
    for (int knt = 0; knt < 2; ++knt) {                                                 \
      _Pragma("unroll")                                                                 \
      for (int ksd = 0; ksd < 2; ++ksd) {                                               \
        const int cc = ((ksd * 4 + quad) ^ (m & 7)) * 8;                                \
        const bf8 kf = *(const bf8*)&k_lds[STG][(half * 32 + knt * 16 + m) * 64 + cc];  \
        s_acc[knt][0] = __builtin_amdgcn_mfma_f32_16x16x32_bf16(kf, qf[0][ksd], s_acc[knt][0], 0, 0, 0); \
        s_acc[knt][1] = __builtin_amdgcn_mfma_f32_16x16x32_bf16(kf, qf[1][ksd], s_acc[knt][1], 0, 0, 0); \
      }                                                                                 \
    }                                                                                   \
    __builtin_amdgcn_s_setprio(0);                                                      \
    bf8 pf[2];  /* [qsub]; slots half*32 + quad*8 + knt*4 + r -> elem knt*4+r */        \
    _Pragma("unroll")                                                                   \
    for (int qsub = 0; qsub < 2; ++qsub) {                                              \
      union { bf8 v; unsigned int w[4]; } pu;                                           \
      _Pragma("unroll")                                                                 \
      for (int knt = 0; knt < 2; ++knt) {                                               \
        const float p0 = fast_exp2(s_acc[knt][qsub][0]);                                \
        const float p1 = fast_exp2(s_acc[knt][qsub][1]);                                \
        const float p2 = fast_exp2(s_acc[knt][qsub][2]);                                \
        const float p3 = fast_exp2(s_acc[knt][qsub][3]);                                \
        psum[qsub] += (p0 + p1) + (p2 + p3);                                            \
        pu.w[knt * 2 + 0] = (unsigned int)f2bfr(p0) | ((unsigned int)f2bfr(p1) << 16);  \
        pu.w[knt * 2 + 1] = (unsigned int)f2bfr(p2) | ((unsigned int)f2bfr(p3) << 16);  \
      }                                                                                 \
      pf[qsub] = pu.v;                                                                  \
    }                                                                                   \
    __builtin_amdgcn_s_setprio(1);                                                      \
    _Pragma("unroll")                                                                   \
    for (int nt = 0; nt < 4; ++nt) {                                                    \
      const int cc = ((half * 4 + quad) ^ (m & 7)) * 8;                                 \
      const bf8 vf = *(const bf8*)&v_lds[STG][(nt * 16 + m) * 64 + cc];                 \
      o_acc[nt][0] = __builtin_amdgcn_mfma_f32_16x16x32_bf16(vf, pf[0], o_acc[nt][0], 0, 0, 0); \
      o_acc[nt][1] = __builtin_amdgcn_mfma_f32_16x16x32_bf16(vf, pf[1], o_acc[nt][1], 0, 0, 0); \
    }                                                                                   \
    __builtin_amdgcn_s_setprio(0);                                                      \
  }

  // bodies 0..23 (always issue i+2 <= 25), then peeled 24 (issues 26), 25, 26 (drain).
  for (int ip = 0; ip < 8; ++ip) {
    const int i0 = ip * 3;
    ATTN_BODY(i0 + 0, 0, 2, true)
    ATTN_BODY(i0 + 1, 1, 2, true)
    ATTN_BODY(i0 + 2, 2, 2, true)
  }
  ATTN_BODY(24, 0, 2, true)
  ATTN_BODY(25, 1, 2, false)
  ATTN_BODY(26, 2, 0, false)
#undef ATTN_BODY
#undef ISSUE_TILE

  // ---- cross-pair reduction: wave w (half 0) += wave w+4 (half 1), via freed staging LDS ----
  __syncthreads();                                // all waves done reading stage LDS
  {
    float* red = (float*)&k_lds[0][0];            // 48 KB raw scratch; need 36 KB
    const int sid = qg * 64 + lane;               // 0..255, stride 36 floats (144 B, 16B-aligned)
    float* slot = red + sid * 36;
    if (half == 1) {
#pragma unroll
      for (int qsub = 0; qsub < 2; ++qsub) {
#pragma unroll
        for (int nt = 0; nt < 4; ++nt)
          *(f4*)(slot + (qsub * 4 + nt) * 4) = o_acc[nt][qsub];
        slot[32 + qsub] = psum[qsub];
      }
    }
    __syncthreads();
    if (half == 1) return;                        // half-1 waves done
#pragma unroll
    for (int qsub = 0; qsub < 2; ++qsub) {
#pragma unroll
      for (int nt = 0; nt < 4; ++nt) {
        const f4 po = *(const f4*)(slot + (qsub * 4 + nt) * 4);
        o_acc[nt][qsub] += po;
      }
      psum[qsub] += slot[32 + qsub];
    }
  }

  // ---- epilogue: denominator = sum over the 4 quads holding q=m, then out += O^T / l ----
  // o_acc[nt][qsub][r] = O[q = qt*128+qg*32+qsub*16+m][d = nt*16+quad*4+r] -> float4 RMW per nt
#pragma unroll
  for (int qsub = 0; qsub < 2; ++qsub) {
    float s = psum[qsub];
    s += __shfl_xor(s, 16);
    s += __shfl_xor(s, 32);
    const float inv = 1.0f / s;
    const int rowq = qt * 128 + qg * 32 + qsub * 16 + m;
    if (rowq < LL) {
      float* op = out + ((size_t)b * LL + rowq) * CC + h * HD + quad * 4;
#pragma unroll
      for (int nt = 0; nt < 4; ++nt) {
        float4 o4 = *(float4*)&op[nt * 16];
        o4.x += o_acc[nt][qsub][0] * inv;
        o4.y += o_acc[nt][qsub][1] * inv;
        o4.z += o_acc[nt][qsub][2] * inv;
        o4.w += o_acc[nt][qsub][3] * inv;
        *(float4*)&op[nt * 16] = o4;
      }
    }
  }
}

extern "C" void kernel_launch(void* const* d_in, const int* in_sizes, int n_in,
                              void* d_out, int out_size, void* d_ws, size_t ws_size,
                              hipStream_t stream) {
  (void)in_sizes; (void)n_in; (void)ws_size; (void)out_size;
  const float* qkv = (const float*)d_in[0];
  const float* lepe_w = (const float*)d_in[1];
  const float* lepe_b = (const float*)d_in[2];
  float* out = (float*)d_out;

  const size_t NE = (size_t)BATCH * LL * CC;
  unsigned short* qb = (unsigned short*)d_ws;
  unsigned short* kb = qb + NE;
  unsigned short* vT = kb + NE;  // 3*NE*2 B ~ 31.9 MB of ws

  combined_kernel<<<dim3(NLEPE + NPREP), 256, 0, stream>>>(qkv, lepe_w, lepe_b, qb, kb, vT, out);
  attn_kernel<<<dim3(672), 512, 0, stream>>>(qb, kb, vT, out);
}

// Round 11
// 168.310 us; speedup vs baseline: 2.2038x; 1.0026x over previous
//
#include <hip/hip_runtime.h>

#define RR 12
#define LL 1728
#define CC 768
#define HEADS 12
#define HD 64
#define BATCH 4

typedef __attribute__((ext_vector_type(8))) short bf8;   // 8 x bf16
typedef __attribute__((ext_vector_type(4))) float f4;    // 4 x fp32

__device__ inline unsigned short f2bf(float x) {         // RNE-ish
  unsigned int u = __float_as_uint(x);
  return (unsigned short)((u + 0x7FFFu + ((u >> 16) & 1u)) >> 16);
}
__device__ inline unsigned short f2bfr(float x) {        // round-half-up (cheap)
  return (unsigned short)((__float_as_uint(x) + 0x8000u) >> 16);
}

__device__ inline float fast_exp2(float x) {
#if __has_builtin(__builtin_amdgcn_exp2f)
  return __builtin_amdgcn_exp2f(x);
#else
  return exp2f(x);
#endif
}

// async 16B global->LDS (wave-uniform LDS base + lane*16)
__device__ inline void gld16(const unsigned short* g, unsigned short* l) {
  __builtin_amdgcn_global_load_lds((const __attribute__((address_space(1))) unsigned int*)g,
                                   (__attribute__((address_space(3))) unsigned int*)l, 16, 0, 0);
}

#define QSCALE 0.1803368801111244f  /* 0.125 * log2(e): folds softmax base-2 conversion in */

#define NLEPE 1296  /* 3 xg x 3 yg x 12 z x 3 ctiles x 4 batch (4x4 y,x patch per block) */
#define NPREP 1296  /* 27 ltiles x 12 heads x 4 batch */

// ---------------- combined prep + lepe (block-uniform partition; R10-proven, unchanged) -----------
// blocks [0, NLEPE): LePE depthwise conv as 4x4 (y,x) patches with z-plane accumulation.
// blocks [NLEPE, NLEPE+NPREP): q,k -> bf16 (q pre-scaled by QSCALE); v -> vT[b][h][d][sigma(k)].
// Slot permutation (for swapped-QK in-register P):
//   sigma(k) with k = nt*16 + quad*4 + r  ->  slot = (nt>>1)*32 + quad*8 + (nt&1)*4 + r
// sigma maps kv rows 0..31 -> slots 0..31 and 32..63 -> 32..63: a kv-HALF of the tile is exactly
// one K=32 PV fragment — used by the attn kernel's wave-pair kv-split.
__global__ __launch_bounds__(256) void combined_kernel(const float* __restrict__ qkv,
                                                       const float* __restrict__ w,
                                                       const float* __restrict__ bias,
                                                       unsigned short* __restrict__ qb,
                                                       unsigned short* __restrict__ kb,
                                                       unsigned short* __restrict__ vT,
                                                       float* __restrict__ out) {
  __shared__ __align__(16) unsigned char smem[27648];  // union: lepe w-stage 27 KB / prep tl 8.3 KB
  const int bid = blockIdx.x;
  const int t = threadIdx.x;

  if (bid < NLEPE) {
    // ================= LePE: 4x4 (y,x) patch, z-plane accumulation =================
    const int xg = (bid % 3) * 4;            // x0 in {0,4,8}
    const int yg = ((bid / 3) % 3) * 4;      // y0 in {0,4,8}
    const int z = (bid / 9) % RR;
    const int ct = (bid / 108) % 3;          // c-tile
    const int b = bid / 324;
    const int c0 = ct * 256;
    const int c = c0 + t;
    float* w_lds = (float*)smem;

    // coalesced stage of w[c0*27 .. (c0+256)*27) as float4 (6912 floats)
    {
      const float* wsrc = w + (size_t)c0 * 27;
#pragma unroll
      for (int i = 0; i < 7; ++i) {
        const int idx = i * 256 + t;         // float4 index, 0..1727
        if (idx < 1728) *(float4*)&w_lds[idx * 4] = *(const float4*)&wsrc[idx * 4];
      }
    }
    __syncthreads();
    float wreg[27];
#pragma unroll
    for (int j = 0; j < 27; ++j) wreg[j] = w_lds[t * 27 + j];  // stride 27 ⊥ 32: 2-way, free

    const float* vb = qkv + ((size_t)(2 * BATCH + b)) * LL * CC + c;
    const float bv = bias[c];
    float acc[4][4];
#pragma unroll
    for (int yy = 0; yy < 4; ++yy)
#pragma unroll
      for (int xx = 0; xx < 4; ++xx) acc[yy][xx] = bv;

#pragma unroll
    for (int dzp = 0; dzp < 3; ++dzp) {
      const int zp = z + dzp - 1;
      const bool zok = (unsigned)zp < RR;    // block-uniform
      // 6x6 halo window: y' = yg-1+wy, x' = xg-1+wx; masked address-safe loads
      float vwin[6][6];
#pragma unroll
      for (int wy = 0; wy < 6; ++wy) {
        const int yp = yg - 1 + wy;
        const bool yok = zok & ((unsigned)yp < RR);
        const int rowbase = (zp * RR + yp) * RR;
#pragma unroll
        for (int wx = 0; wx < 6; ++wx) {
          const int xp = xg - 1 + wx;
          const bool ok = yok & ((unsigned)xp < RR);
          const int lp = ok ? rowbase + xp : 0;
          const float vv = vb[(size_t)lp * CC];
          vwin[wy][wx] = ok ? vv : 0.f;
        }
      }
      // accumulate the 9 in-plane taps
#pragma unroll
      for (int dy = 0; dy < 3; ++dy) {
        const float w0 = wreg[dzp * 9 + dy * 3 + 0];
        const float w1 = wreg[dzp * 9 + dy * 3 + 1];
        const float w2 = wreg[dzp * 9 + dy * 3 + 2];
#pragma unroll
        for (int yy = 0; yy < 4; ++yy) {
#pragma unroll
          for (int xx = 0; xx < 4; ++xx)
            acc[yy][xx] += w0 * vwin[yy + dy][xx] + w1 * vwin[yy + dy][xx + 1] +
                           w2 * vwin[yy + dy][xx + 2];
        }
      }
    }
#pragma unroll
    for (int yy = 0; yy < 4; ++yy) {
      const size_t obase = ((size_t)b * LL + (z * RR + yg + yy) * RR + xg) * CC + c;
#pragma unroll
      for (int xx = 0; xx < 4; ++xx) out[obase + (size_t)xx * CC] = acc[yy][xx];
    }

  } else {
    // ================= prep =================
    const int p = bid - NLEPE;
    const int lt = p % 27;
    const int h = (p / 27) % HEADS;
    const int b = p / (27 * HEADS);
    unsigned short* tl = (unsigned short*)smem;  // [d][l_local], stride 65

    // ---- q/k bf16 conversion for rows lt*64.., cols h*64.. ----
    {
      const int r0 = t >> 4;             // 0..15
      const int c4 = (t & 15) * 4;       // 0..60
#pragma unroll
      for (int pi = 0; pi < 4; ++pi) {
        const int row = lt * 64 + pi * 16 + r0;
        const size_t off = ((size_t)b * LL + row) * CC + h * HD + c4;
        const float4 qv = *(const float4*)(qkv + off);
        ushort4 oq;
        oq.x = f2bf(qv.x * QSCALE); oq.y = f2bf(qv.y * QSCALE);
        oq.z = f2bf(qv.z * QSCALE); oq.w = f2bf(qv.w * QSCALE);
        *(ushort4*)(qb + off) = oq;
        const float4 kv = *(const float4*)(qkv + (size_t)BATCH * LL * CC + off);
        ushort4 ok;
        ok.x = f2bf(kv.x); ok.y = f2bf(kv.y); ok.z = f2bf(kv.z); ok.w = f2bf(kv.w);
        *(ushort4*)(kb + off) = ok;
      }
    }

    // ---- vT with slot permutation ----
    const float* vsrc = qkv + ((size_t)(2 * BATCH + b)) * LL * CC;
#pragma unroll
    for (int it = 0; it < 4; ++it) {
      const int idx = it * 256 + t;
      const int lrow = idx >> 4;
      const int c4 = (idx & 15) * 4;
      const float4 vv = *(const float4*)(vsrc + (size_t)(lt * 64 + lrow) * CC + h * HD + c4);
      tl[(c4 + 0) * 65 + lrow] = f2bf(vv.x);
      tl[(c4 + 1) * 65 + lrow] = f2bf(vv.y);
      tl[(c4 + 2) * 65 + lrow] = f2bf(vv.z);
      tl[(c4 + 3) * 65 + lrow] = f2bf(vv.w);
    }
    __syncthreads();
#pragma unroll
    for (int it = 0; it < 4; ++it) {
      const int idx = it * 256 + t;
      const int drow = idx >> 4;
      const int u = idx & 15;            // slot group: s4 = u*4
      const int s4 = u * 4;
      // slots s4..s4+3 hold physical kv rows kbase..kbase+3 (consecutive):
      //   kbase = ((u>>3)*2 + (u&1))*16 + ((u>>1)&3)*4
      const int kbase = (((u >> 3) * 2 + (u & 1)) << 4) + (((u >> 1) & 3) << 2);
      ushort4 o;
      o.x = tl[drow * 65 + kbase + 0];
      o.y = tl[drow * 65 + kbase + 1];
      o.z = tl[drow * 65 + kbase + 2];
      o.w = tl[drow * 65 + kbase + 3];
      *(ushort4*)(vT + (((size_t)(b * HEADS + h) * HD + drow) * LL) + lt * 64 + s4) = o;
    }
  }
}

// ---------------- Flash attention: 2-stage 32KB LDS -> 4 blocks/CU (32 waves/CU) -----------------
// R10 attn: MfmaUtil 25% = exactly the 15us MFMA floor over 61.5us; invariant to ds_read halvings
// (R2, R8) and traffic cuts -> the untested lever is TLP. Dropping stage 3: LDS 49152 -> 32768,
// __launch_bounds__(512,4) (VGPR cap 64; body measured 60 in R8/R10 -> fits, no spill) gives
// 4 blocks/CU = 32 waves/CU, still one residency round (1024 slots >= 672 blocks).
// Pipeline: prefetch depth 1 — vmcnt(0) is EXACT (only own tile's 2 loads outstanding); order
// stays wait -> barrier -> issue (R3-proven). Issue of tile i+1 lands in the stage read at i-1,
// freed by the barrier. Wave-pair kv-split + in-register P (sigma) unchanged from R8.
// Epilogue: two-pass (per-qsub) cross-pair reduction in the single contiguous 32KB smem_all
// (20-float stride x 256 slots = 20.5KB <= 32KB guaranteed-adjacent scratch).
__global__ __launch_bounds__(512, 4) void attn_kernel(const unsigned short* __restrict__ qb,
                                                      const unsigned short* __restrict__ kb,
                                                      const unsigned short* __restrict__ vT,
                                                      float* __restrict__ out) {
  __shared__ __align__(16) unsigned short smem_all[16384];  // 32 KB: k[2][4096] | v[2][4096]
  unsigned short* const k_base = smem_all;                  // + stage*4096
  unsigned short* const v_base = smem_all + 8192;           // + stage*4096

  // XCD-affine decode: g&7 = XCD (round-robin dispatch), 84 slots per XCD = 6 bh x 14 qt.
  const int g = blockIdx.x;
  const int xcd = g & 7;
  const int ix = g >> 3;                         // 0..83
  const int qt = ix % 14;                        // 0..13 (qt 13 is a half tile)
  const int bh = xcd * 6 + ix / 14;              // 0..47
  const int h = bh % HEADS;
  const int b = bh / HEADS;
  const int stg = (qt * 2) % 27;                 // KV start tile (stagger)

  const int t = threadIdx.x;
  const int lane = t & 63;
  const int wave = t >> 6;                       // 0..7
  const int m = lane & 15;
  const int quad = lane >> 4;
  const int half = wave >> 2;                    // kv-half this wave computes
  const int qg = wave & 3;                       // q-group (32 q-rows)

  // Q frags (pre-scaled bf16); B-operand layout: lane&15 = q col, ksd*32+quad*8 = d-slice
  bf8 qf[2][2];                                  // [qsub][ksd]
#pragma unroll
  for (int qsub = 0; qsub < 2; ++qsub) {
    int row = qt * 128 + qg * 32 + qsub * 16 + m;
    row = row < LL ? row : LL - 1;               // clamp for the qt==13 half tile
    const size_t qbase = ((size_t)(b * LL + row)) * CC + h * HD;
    qf[qsub][0] = *(const bf8*)(qb + qbase + quad * 8);
    qf[qsub][1] = *(const bf8*)(qb + qbase + 32 + quad * 8);
  }

  // DMA source offsets: chunk cidx = wave*64+lane (512 chunks = one 8KB matrix);
  // row = cidx>>3; src chunk = (cidx&7)^(row&7)  (XOR swizzle, read side matches)
  int koff, voff, ldsb;
  {
    const int cidx = wave * 64 + lane;
    const int row = cidx >> 3;
    const int sc = (cidx & 7) ^ (row & 7);
    koff = row * CC + sc * 8;
    voff = row * LL + sc * 8;
    ldsb = wave * 512;
  }

  const unsigned short* kgb = kb + (size_t)b * LL * CC + h * HD;
  const unsigned short* vgb = vT + ((size_t)(b * HEADS + h) * HD) * LL;

#define ISSUE_TILE(KT, BUF)                                                             \
  {                                                                                     \
    gld16(kgb + (size_t)(KT) * (64 * CC) + koff, k_base + (BUF) * 4096 + ldsb);         \
    gld16(vgb + (KT) * 64 + voff, v_base + (BUF) * 4096 + ldsb);                        \
  }

  // prologue: tile stg -> stage 0 (2 loads/wave in flight)
  ISSUE_TILE(stg, 0)

  f4 o_acc[4][2] = {};          // [nt(d-group)][qsub]; covers this wave's kv-half only
  float psum[2] = {0.f, 0.f};   // per-lane partial denominator, per q-subtile (kv-half only)

  // body i: physical tile (stg+i)%27 on stage i&1.
  // vmcnt(0): own tile-i loads landed (EXACT: nothing else outstanding at depth-1 prefetch);
  // barrier: ALL waves' tile-i loads landed AND stage (i&1)^1 (read in body i-1) is free;
  // then issue tile i+1 into it — its DMA flies under this body's compute.
#define ATTN_BODY(I, STG, DOISSUE)                                                      \
  {                                                                                     \
    __asm__ volatile("s_waitcnt vmcnt(0)" ::: "memory");                                \
    __builtin_amdgcn_s_barrier();                                                       \
    if (DOISSUE) {                                                                      \
      int ktn = stg + (I) + 1; if (ktn >= 27) ktn -= 27;                                \
      ISSUE_TILE(ktn, (STG) ^ 1)                                                        \
    }                                                                                   \
    f4 s_acc[2][2] = {};  /* [knt(16 kv within half)][qsub] */                          \
    __builtin_amdgcn_s_setprio(1);                                                      \
    _Pragma("unroll")                                                                   \
    for (int knt = 0; knt < 2; ++knt) {                                                 \
      _Pragma("unroll")                                                                 \
      for (int ksd = 0; ksd < 2; ++ksd) {                                               \
        const int cc = ((ksd * 4 + quad) ^ (m & 7)) * 8;                                \
        const bf8 kf = *(const bf8*)&k_base[(STG) * 4096 + (half * 32 + knt * 16 + m) * 64 + cc]; \
        s_acc[knt][0] = __builtin_amdgcn_mfma_f32_16x16x32_bf16(kf, qf[0][ksd], s_acc[knt][0], 0, 0, 0); \
        s_acc[knt][1] = __builtin_amdgcn_mfma_f32_16x16x32_bf16(kf, qf[1][ksd], s_acc[knt][1], 0, 0, 0); \
      }                                                                                 \
    }                                                                                   \
    __builtin_amdgcn_s_setprio(0);                                                      \
    bf8 pf[2];  /* [qsub]; slots half*32 + quad*8 + knt*4 + r -> elem knt*4+r */        \
    _Pragma("unroll")                                                                   \
    for (int qsub = 0; qsub < 2; ++qsub) {                                              \
      union { bf8 v; unsigned int w[4]; } pu;                                           \
      _Pragma("unroll")                                                                 \
      for (int knt = 0; knt < 2; ++knt) {                                               \
        const float p0 = fast_exp2(s_acc[knt][qsub][0]);                                \
        const float p1 = fast_exp2(s_acc[knt][qsub][1]);                                \
        const float p2 = fast_exp2(s_acc[knt][qsub][2]);                                \
        const float p3 = fast_exp2(s_acc[knt][qsub][3]);                                \
        psum[qsub] += (p0 + p1) + (p2 + p3);                                            \
        pu.w[knt * 2 + 0] = (unsigned int)f2bfr(p0) | ((unsigned int)f2bfr(p1) << 16);  \
        pu.w[knt * 2 + 1] = (unsigned int)f2bfr(p2) | ((unsigned int)f2bfr(p3) << 16);  \
      }                                                                                 \
      pf[qsub] = pu.v;                                                                  \
    }                                                                                   \
    __builtin_amdgcn_s_setprio(1);                                                      \
    _Pragma("unroll")                                                                   \
    for (int nt = 0; nt < 4; ++nt) {                                                    \
      const int cc = ((half * 4 + quad) ^ (m & 7)) * 8;                                 \
      const bf8 vf = *(const bf8*)&v_base[(STG) * 4096 + (nt * 16 + m) * 64 + cc];      \
      o_acc[nt][0] = __builtin_amdgcn_mfma_f32_16x16x32_bf16(vf, pf[0], o_acc[nt][0], 0, 0, 0); \
      o_acc[nt][1] = __builtin_amdgcn_mfma_f32_16x16x32_bf16(vf, pf[1], o_acc[nt][1], 0, 0, 0); \
    }                                                                                   \
    __builtin_amdgcn_s_setprio(0);                                                      \
  }

  // bodies 0..25 (issue i+1), body 26 (drain)
  for (int ip = 0; ip < 13; ++ip) {
    const int i0 = ip * 2;
    ATTN_BODY(i0 + 0, 0, true)
    ATTN_BODY(i0 + 1, 1, (i0 + 1) < 26)
  }
  ATTN_BODY(26, 0, false)
#undef ATTN_BODY
#undef ISSUE_TILE

  // ---- cross-pair reduction: wave w (half 0) += wave w+4 (half 1), two passes (fits 32 KB) ----
  __syncthreads();                                // all waves done reading stage LDS
  {
    float* red = (float*)smem_all;                // 32 KB contiguous scratch
    const int sid = qg * 64 + lane;               // 0..255
    float* slot = red + sid * 20;                 // 80 B stride, 16B-aligned
#pragma unroll
    for (int qsub = 0; qsub < 2; ++qsub) {
      if (half == 1) {
#pragma unroll
        for (int nt = 0; nt < 4; ++nt) *(f4*)(slot + nt * 4) = o_acc[nt][qsub];
        slot[16] = psum[qsub];
      }
      __syncthreads();
      if (half == 0) {
#pragma unroll
        for (int nt = 0; nt < 4; ++nt) o_acc[nt][qsub] += *(const f4*)(slot + nt * 4);
        psum[qsub] += slot[16];
      }
      __syncthreads();                            // reads done before next pass overwrites
    }
  }
  if (half == 1) return;                          // half-1 waves done

  // ---- epilogue: denominator = sum over the 4 quads holding q=m, then out += O^T / l ----
  // o_acc[nt][qsub][r] = O[q = qt*128+qg*32+qsub*16+m][d = nt*16+quad*4+r] -> float4 RMW per nt
#pragma unroll
  for (int qsub = 0; qsub < 2; ++qsub) {
    float s = psum[qsub];
    s += __shfl_xor(s, 16);
    s += __shfl_xor(s, 32);
    const float inv = 1.0f / s;
    const int rowq = qt * 128 + qg * 32 + qsub * 16 + m;
    if (rowq < LL) {
      float* op = out + ((size_t)b * LL + rowq) * CC + h * HD + quad * 4;
#pragma unroll
      for (int nt = 0; nt < 4; ++nt) {
        float4 o4 = *(float4*)&op[nt * 16];
        o4.x += o_acc[nt][qsub][0] * inv;
        o4.y += o_acc[nt][qsub][1] * inv;
        o4.z += o_acc[nt][qsub][2] * inv;
        o4.w += o_acc[nt][qsub][3] * inv;
        *(float4*)&op[nt * 16] = o4;
      }
    }
  }
}

extern "C" void kernel_launch(void* const* d_in, const int* in_sizes, int n_in,
                              void* d_out, int out_size, void* d_ws, size_t ws_size,
                              hipStream_t stream) {
  (void)in_sizes; (void)n_in; (void)ws_size; (void)out_size;
  const float* qkv = (const float*)d_in[0];
  const float* lepe_w = (const float*)d_in[1];
  const float* lepe_b = (const float*)d_in[2];
  float* out = (float*)d_out;

  const size_t NE = (size_t)BATCH * LL * CC;
  unsigned short* qb = (unsigned short*)d_ws;
  unsigned short* kb = qb + NE;
  unsigned short* vT = kb + NE;  // 3*NE*2 B ~ 31.9 MB of ws

  combined_kernel<<<dim3(NLEPE + NPREP), 256, 0, stream>>>(qkv, lepe_w, lepe_b, qb, kb, vT, out);
  attn_kernel<<<dim3(672), 512, 0, stream>>>(qb, kb, vT, out);
}